// Round 1
// baseline (6945.753 us; speedup 1.0000x reference)
//
#include <hip/hip_runtime.h>
#include <cstdint>
#include <cstddef>

// Problem constants
#define TT   64
#define BB   32
#define CINC 64
#define HIDN 128
#define LL   256
#define LPP  128
#define NSAMP (TT*BB)   // 2048
#define LN_EPS 1e-5f

// ---------- small helpers ----------
__device__ __forceinline__ float bf2f(unsigned short u){
    union { unsigned int i; float f; } v; v.i = ((unsigned int)u) << 16; return v.f;
}
__device__ __forceinline__ unsigned short f2bf(float f){
    union { float f; unsigned int i; } v; v.f = f;
    unsigned int u = v.i;
    u = (u + 0x7FFFu + ((u >> 16) & 1u)) >> 16;   // RTNE
    return (unsigned short)u;
}
__device__ __forceinline__ float sigmoidf_(float x){ return 1.f/(1.f + __expf(-x)); }
__device__ __forceinline__ float tanhf_(float x){ return 1.f - 2.f/(__expf(2.f*x) + 1.f); }

// =====================================================================
// Phase 1: per (sample, gate): conv1d(x, wx) + bx -> LayerNorm([HID,L]) ->
// maxpool2 -> write bf16 to ws.
// Block: 256 threads = 4 waves. Wave w handles rows o = w*32..w*32+31.
// Lane handles l = 4*lane .. 4*lane+3 (so pooling is intra-lane).
// Accumulators: 32 rows x 4 l = 128 VGPRs per thread.
// Weights are wave-uniform -> s_load (SGPR operand to v_fma).
// =====================================================================
__global__ __launch_bounds__(256, 2) void phase1_kernel(
    const float* __restrict__ x,
    const float* __restrict__ wx0, const float* __restrict__ bx0,
    const float* __restrict__ wx1, const float* __restrict__ bx1,
    const float* __restrict__ wx2, const float* __restrict__ bx2,
    const float* __restrict__ wx3, const float* __restrict__ bx3,
    const float* __restrict__ lnw, const float* __restrict__ lnb,
    unsigned int* __restrict__ xg)     // [4][NSAMP][HID][LP/2] dwords (2x bf16)
{
    const int s = blockIdx.x;          // sample (t*B+b)
    const int g = blockIdx.y;          // gate

    const float* W; const float* Bv;
    if (g == 0)      { W = wx0; Bv = bx0; }
    else if (g == 1) { W = wx1; Bv = bx1; }
    else if (g == 2) { W = wx2; Bv = bx2; }
    else             { W = wx3; Bv = bx3; }

    const int tid  = threadIdx.x;
    const int lane = tid & 63;
    // force wave index scalar so weight addressing scalarizes to s_load
    const int wv    = __builtin_amdgcn_readfirstlane(tid >> 6);
    const int obase = wv * 32;

    const float* xs = x + (size_t)s * (CINC * LL);
    const int l0 = lane * 4;

    float acc[32][4];
    #pragma unroll
    for (int r = 0; r < 32; r++){ acc[r][0]=0.f; acc[r][1]=0.f; acc[r][2]=0.f; acc[r][3]=0.f; }

    for (int c = 0; c < CINC; c++){
        const float* xr = xs + c * LL;
        float xv[6];
        #pragma unroll
        for (int d = 0; d < 6; d++){
            int l = l0 + d - 1;
            xv[d] = (l >= 0 && l < LL) ? xr[l] : 0.f;
        }
        const float* wc = W + (size_t)c * 3;
        #pragma unroll
        for (int r = 0; r < 32; r++){
            const int o = obase + r;
            const float* wo = wc + (size_t)o * (CINC * 3);
            const float w0 = wo[0], w1 = wo[1], w2 = wo[2];
            #pragma unroll
            for (int q = 0; q < 4; q++){
                acc[r][q] += w0 * xv[q] + w1 * xv[q+1] + w2 * xv[q+2];
            }
        }
    }

    // bias + local stats
    float sum = 0.f, ssq = 0.f;
    #pragma unroll
    for (int r = 0; r < 32; r++){
        const float bo = Bv[obase + r];
        #pragma unroll
        for (int q = 0; q < 4; q++){
            float v = acc[r][q] + bo;
            acc[r][q] = v;
            sum += v; ssq += v * v;
        }
    }

    // wave reduce (64 lanes)
    #pragma unroll
    for (int off = 32; off > 0; off >>= 1){
        sum += __shfl_down(sum, off, 64);
        ssq += __shfl_down(ssq, off, 64);
    }
    __shared__ float red[8];
    if (lane == 0){ red[wv] = sum; red[4 + wv] = ssq; }
    __syncthreads();
    const float ts = red[0] + red[1] + red[2] + red[3];
    const float tq = red[4] + red[5] + red[6] + red[7];
    const float mu  = ts * (1.f / 32768.f);
    const float var = tq * (1.f / 32768.f) - mu * mu;
    const float inv = rsqrtf(var + LN_EPS);

    // normalize + affine + maxpool2 + bf16-pack store (coalesced dwords)
    unsigned int* outb = xg + ((size_t)g * NSAMP + s) * (HIDN * (LPP/2));
    #pragma unroll
    for (int r = 0; r < 32; r++){
        const int o = obase + r;
        const float4 lw = *(const float4*)(lnw + (size_t)o * LL + l0);
        const float4 lb = *(const float4*)(lnb + (size_t)o * LL + l0);
        const float v0 = (acc[r][0] - mu) * inv * lw.x + lb.x;
        const float v1 = (acc[r][1] - mu) * inv * lw.y + lb.y;
        const float v2 = (acc[r][2] - mu) * inv * lw.z + lb.z;
        const float v3 = (acc[r][3] - mu) * inv * lw.w + lb.w;
        const float p0 = fmaxf(v0, v1);
        const float p1 = fmaxf(v2, v3);
        const unsigned int pk = (unsigned int)f2bf(p0) | ((unsigned int)f2bf(p1) << 16);
        outb[(size_t)o * (LPP/2) + lane] = pk;
    }
}

// =====================================================================
// Phase 2 (one launch per timestep): hc = conv1d(h_prev, wh)+bh for all 4
// gates, combine with precomputed x-gates, update c, write h to d_out[t].
// Grid: (B, 32 hid-quads, 2 l-halves); block = 1 wave (64 threads).
// Lane owns (4 gates x 4 hid) at one l. Weights wave-uniform -> s_load.
// =====================================================================
__global__ __launch_bounds__(64) void phase2_kernel(
    const float* __restrict__ hprev,          // [B][HID][LP] or ignored when first
    const unsigned short* __restrict__ xg,    // [4][NSAMP][HID][LP] bf16
    const float* __restrict__ wh0, const float* __restrict__ bh0,
    const float* __restrict__ wh1, const float* __restrict__ bh1,
    const float* __restrict__ wh2, const float* __restrict__ bh2,
    const float* __restrict__ wh3, const float* __restrict__ bh3,
    float* __restrict__ hout,                 // d_out + t*B*HID*LP
    float* __restrict__ cst,                  // [B][HID][LP]
    int t, int first)
{
    const int b    = blockIdx.x;
    const int hq   = blockIdx.y;     // 4 hid channels per block
    const int lh   = blockIdx.z;     // l-half
    const int lane = threadIdx.x;
    const int l    = lh * 64 + lane;

    const float* whp[4] = { wh0, wh1, wh2, wh3 };
    const float* bhp[4] = { bh0, bh1, bh2, bh3 };

    float acc[4][4];
    #pragma unroll
    for (int g = 0; g < 4; g++)
        #pragma unroll
        for (int h = 0; h < 4; h++) acc[g][h] = 0.f;

    if (!first){
        const float* hb = hprev + (size_t)b * (HIDN * LPP);
        for (int c = 0; c < HIDN; c++){
            const float* hr = hb + (size_t)c * LPP;
            const float xm1 = (l > 0)        ? hr[l - 1] : 0.f;
            const float x0  =                  hr[l];
            const float xp1 = (l < LPP - 1)  ? hr[l + 1] : 0.f;
            #pragma unroll
            for (int g = 0; g < 4; g++){
                #pragma unroll
                for (int h = 0; h < 4; h++){
                    const int hid = hq * 4 + h;
                    const float* wo = whp[g] + ((size_t)hid * HIDN + c) * 3;
                    acc[g][h] += wo[0] * xm1 + wo[1] * x0 + wo[2] * xp1;
                }
            }
        }
    }

    const int sidx = t * BB + b;
    float pre[4][4];
    #pragma unroll
    for (int g = 0; g < 4; g++){
        #pragma unroll
        for (int h = 0; h < 4; h++){
            const int hid = hq * 4 + h;
            const float xgv = bf2f(xg[(((size_t)g * NSAMP + sidx) * HIDN + hid) * LPP + l]);
            pre[g][h] = acc[g][h] + bhp[g][hid] + xgv;
        }
    }

    #pragma unroll
    for (int h = 0; h < 4; h++){
        const int hid = hq * 4 + h;
        float* cp = cst + ((size_t)b * HIDN + hid) * LPP + l;
        const float cv = first ? 0.f : *cp;
        const float ig = sigmoidf_(pre[0][h]);
        const float fg = sigmoidf_(pre[1][h]);
        const float gg = tanhf_(pre[2][h]);
        const float og = sigmoidf_(pre[3][h]);
        const float cn = fg * cv + ig * gg;
        *cp = cn;
        hout[((size_t)b * HIDN + hid) * LPP + l] = og * tanhf_(cn);
    }
}

// =====================================================================
// Host side
// =====================================================================
extern "C" void kernel_launch(void* const* d_in, const int* in_sizes, int n_in,
                              void* d_out, int out_size, void* d_ws, size_t ws_size,
                              hipStream_t stream)
{
    const float* x = (const float*)d_in[0];

    // Order-agnostic classification by element counts.
    // wx: HID*CIN*3 = 24576; wh: HID*HID*3 = 49152; biases: 128 (attach to
    // the immediately preceding weight); ln_w then ln_b: HID*L = 32768.
    const float* wxp[4] = {nullptr,nullptr,nullptr,nullptr};
    const float* bxp[4] = {nullptr,nullptr,nullptr,nullptr};
    const float* whp[4] = {nullptr,nullptr,nullptr,nullptr};
    const float* bhp[4] = {nullptr,nullptr,nullptr,nullptr};
    const float* lnw = nullptr; const float* lnb = nullptr;
    int nwx = 0, nwh = 0, pend = -1;  // 0 = wx pending bias, 1 = wh pending bias
    for (int i = 1; i < n_in; i++){
        const float* p = (const float*)d_in[i];
        const int sz = in_sizes[i];
        if (sz == HIDN * CINC * 3)      { wxp[nwx] = p; pend = 0; }
        else if (sz == HIDN * HIDN * 3) { whp[nwh] = p; pend = 1; }
        else if (sz == HIDN)            { if (pend == 0) bxp[nwx++] = p; else bhp[nwh++] = p; pend = -1; }
        else if (sz == HIDN * LL)       { if (!lnw) lnw = p; else lnb = p; }
    }

    // Workspace layout: xg (bf16, 256 MiB) then c-state (fp32, 2 MiB).
    // c-state is written before it is read (t==0 skips the load), so no init
    // is needed despite the 0xAA poison.
    unsigned int*   xg_u32 = (unsigned int*)d_ws;
    unsigned short* xg_u16 = (unsigned short*)d_ws;
    const size_t xg_bytes = (size_t)4 * NSAMP * HIDN * LPP * 2;
    float* cst = (float*)((char*)d_ws + xg_bytes);
    float* out = (float*)d_out;

    phase1_kernel<<<dim3(NSAMP, 4), 256, 0, stream>>>(
        x, wxp[0], bxp[0], wxp[1], bxp[1], wxp[2], bxp[2], wxp[3], bxp[3],
        lnw, lnb, xg_u32);

    for (int t = 0; t < TT; t++){
        const float* hprev = (t == 0) ? out : out + (size_t)(t - 1) * BB * HIDN * LPP;
        phase2_kernel<<<dim3(BB, 32, 2), 64, 0, stream>>>(
            hprev, xg_u16,
            whp[0], bhp[0], whp[1], bhp[1], whp[2], bhp[2], whp[3], bhp[3],
            out + (size_t)t * BB * HIDN * LPP, cst, t, (t == 0) ? 1 : 0);
    }
}

// Round 2
// 4862.123 us; speedup vs baseline: 1.4285x; 1.4285x over previous
//
#include <hip/hip_runtime.h>
#include <cstdint>
#include <cstddef>

// Problem constants
#define TT   64
#define BB   32
#define CINC 64
#define HIDN 128
#define LL   256
#define LPP  128
#define NSAMP (TT*BB)   // 2048
#define LN_EPS 1e-5f

// ---------- small helpers ----------
__device__ __forceinline__ float bf2f(unsigned short u){
    union { unsigned int i; float f; } v; v.i = ((unsigned int)u) << 16; return v.f;
}
__device__ __forceinline__ unsigned short f2bf(float f){
    union { float f; unsigned int i; } v; v.f = f;
    unsigned int u = v.i;
    u = (u + 0x7FFFu + ((u >> 16) & 1u)) >> 16;   // RTNE
    return (unsigned short)u;
}
__device__ __forceinline__ float sigmoidf_(float x){ return 1.f/(1.f + __expf(-x)); }
__device__ __forceinline__ float tanhf_(float x){ return 1.f - 2.f/(__expf(2.f*x) + 1.f); }

// =====================================================================
// Phase 1 (UNCHANGED from round 1): conv1d(x) + LN + maxpool -> bf16 xg.
// =====================================================================
__global__ __launch_bounds__(256, 2) void phase1_kernel(
    const float* __restrict__ x,
    const float* __restrict__ wx0, const float* __restrict__ bx0,
    const float* __restrict__ wx1, const float* __restrict__ bx1,
    const float* __restrict__ wx2, const float* __restrict__ bx2,
    const float* __restrict__ wx3, const float* __restrict__ bx3,
    const float* __restrict__ lnw, const float* __restrict__ lnb,
    unsigned int* __restrict__ xg)     // [4][NSAMP][HID][LP/2] dwords (2x bf16)
{
    const int s = blockIdx.x;          // sample (t*B+b)
    const int g = blockIdx.y;          // gate

    const float* W; const float* Bv;
    if (g == 0)      { W = wx0; Bv = bx0; }
    else if (g == 1) { W = wx1; Bv = bx1; }
    else if (g == 2) { W = wx2; Bv = bx2; }
    else             { W = wx3; Bv = bx3; }

    const int tid  = threadIdx.x;
    const int lane = tid & 63;
    const int wv    = __builtin_amdgcn_readfirstlane(tid >> 6);
    const int obase = wv * 32;

    const float* xs = x + (size_t)s * (CINC * LL);
    const int l0 = lane * 4;

    float acc[32][4];
    #pragma unroll
    for (int r = 0; r < 32; r++){ acc[r][0]=0.f; acc[r][1]=0.f; acc[r][2]=0.f; acc[r][3]=0.f; }

    for (int c = 0; c < CINC; c++){
        const float* xr = xs + c * LL;
        float xv[6];
        #pragma unroll
        for (int d = 0; d < 6; d++){
            int l = l0 + d - 1;
            xv[d] = (l >= 0 && l < LL) ? xr[l] : 0.f;
        }
        const float* wc = W + (size_t)c * 3;
        #pragma unroll
        for (int r = 0; r < 32; r++){
            const int o = obase + r;
            const float* wo = wc + (size_t)o * (CINC * 3);
            const float w0 = wo[0], w1 = wo[1], w2 = wo[2];
            #pragma unroll
            for (int q = 0; q < 4; q++){
                acc[r][q] += w0 * xv[q] + w1 * xv[q+1] + w2 * xv[q+2];
            }
        }
    }

    float sum = 0.f, ssq = 0.f;
    #pragma unroll
    for (int r = 0; r < 32; r++){
        const float bo = Bv[obase + r];
        #pragma unroll
        for (int q = 0; q < 4; q++){
            float v = acc[r][q] + bo;
            acc[r][q] = v;
            sum += v; ssq += v * v;
        }
    }

    #pragma unroll
    for (int off = 32; off > 0; off >>= 1){
        sum += __shfl_down(sum, off, 64);
        ssq += __shfl_down(ssq, off, 64);
    }
    __shared__ float red[8];
    if (lane == 0){ red[wv] = sum; red[4 + wv] = ssq; }
    __syncthreads();
    const float ts = red[0] + red[1] + red[2] + red[3];
    const float tq = red[4] + red[5] + red[6] + red[7];
    const float mu  = ts * (1.f / 32768.f);
    const float var = tq * (1.f / 32768.f) - mu * mu;
    const float inv = rsqrtf(var + LN_EPS);

    unsigned int* outb = xg + ((size_t)g * NSAMP + s) * (HIDN * (LPP/2));
    #pragma unroll
    for (int r = 0; r < 32; r++){
        const int o = obase + r;
        const float4 lw = *(const float4*)(lnw + (size_t)o * LL + l0);
        const float4 lb = *(const float4*)(lnb + (size_t)o * LL + l0);
        const float v0 = (acc[r][0] - mu) * inv * lw.x + lb.x;
        const float v1 = (acc[r][1] - mu) * inv * lw.y + lb.y;
        const float v2 = (acc[r][2] - mu) * inv * lw.z + lb.z;
        const float v3 = (acc[r][3] - mu) * inv * lw.w + lb.w;
        const float p0 = fmaxf(v0, v1);
        const float p1 = fmaxf(v2, v3);
        const unsigned int pk = (unsigned int)f2bf(p0) | ((unsigned int)f2bf(p1) << 16);
        outb[(size_t)o * (LPP/2) + lane] = pk;
    }
}

// =====================================================================
// Phase 2 (REDESIGNED): weights staged to LDS once per block per step,
// transposed to [c3k=c*3+k][gate][hid4] with slot swizzle so the hot loop
// reads wave-uniform ds_read_b128 (broadcast, conflict-free) and does pure
// VGPR v_fma_f32 -- no s_load chain in the K-loop.
// Block = 128 threads (thread = l), grid = (B=32, hq=32). Lane owns
// (4 gates x 4 hid) at its l.
// =====================================================================
__global__ __launch_bounds__(128) void phase2_kernel(
    const float* __restrict__ hprev,          // [B][HID][LP]
    const unsigned short* __restrict__ xg,    // [4][NSAMP][HID][LP] bf16
    const float* __restrict__ wh0, const float* __restrict__ bh0,
    const float* __restrict__ wh1, const float* __restrict__ bh1,
    const float* __restrict__ wh2, const float* __restrict__ bh2,
    const float* __restrict__ wh3, const float* __restrict__ bh3,
    float* __restrict__ hout,                 // d_out + t*B*HID*LP
    float* __restrict__ cst,                  // [B][HID][LP]
    int t, int first)
{
    const int b   = blockIdx.x;
    const int hq  = blockIdx.y;      // 4 hid channels per block
    const int tid = threadIdx.x;     // = l, 0..127
    const int l   = tid;

    // LDS: [384 c3k][4 slot][4 h] floats = 24 KB. slot = (g + (c3k>>2)) & 3.
    __shared__ float wlds[384 * 16];

    float acc[4][4];
    #pragma unroll
    for (int g = 0; g < 4; g++)
        #pragma unroll
        for (int h = 0; h < 4; h++) acc[g][h] = 0.f;

    if (!first){
        // ---- stage weights: 16 rows (g,h) x 384 floats, coalesced float4
        // global reads, transposed scalar LDS writes (swizzled slot). ----
        // j in [0,1536): r = j/96 (row = g*4+h), p = j%96 (float4 within row)
        #pragma unroll
        for (int it = 0; it < 12; ++it){
            const int j = tid + 128 * it;
            const int r = j / 96;
            const int p = j - r * 96;
            const int g = r >> 2, h = r & 3;
            const float* Wg = (g == 0) ? wh0 : (g == 1) ? wh1 : (g == 2) ? wh2 : wh3;
            const float4 v = *(const float4*)(Wg + ((size_t)(hq * 4 + h)) * 384 + p * 4);
            const int s = (g + p) & 3;              // swizzle key = (c3k>>2)&3 == p&3
            const int base = (p * 4) * 16 + s * 4 + h;
            wlds[base]      = v.x;   // c3k = 4p+0
            wlds[base + 16] = v.y;   // c3k = 4p+1
            wlds[base + 32] = v.z;   // c3k = 4p+2
            wlds[base + 48] = v.w;   // c3k = 4p+3
        }
        __syncthreads();

        const float* hb = hprev + (size_t)b * (HIDN * LPP);
        const float4* wlds4 = (const float4*)wlds;
        #pragma unroll 2
        for (int c = 0; c < HIDN; c++){
            const float* hr = hb + c * LPP;
            const float hv0 = (l > 0)       ? hr[l - 1] : 0.f;
            const float hv1 =                 hr[l];
            const float hv2 = (l < LPP - 1) ? hr[l + 1] : 0.f;
            #pragma unroll
            for (int k = 0; k < 3; k++){
                const float hk = (k == 0) ? hv0 : (k == 1) ? hv1 : hv2;
                const int c3k = c * 3 + k;
                #pragma unroll
                for (int g = 0; g < 4; g++){
                    const int s = (g + ((c3k >> 2) & 3)) & 3;
                    const float4 w = wlds4[c3k * 4 + s];
                    acc[g][0] += w.x * hk;
                    acc[g][1] += w.y * hk;
                    acc[g][2] += w.z * hk;
                    acc[g][3] += w.w * hk;
                }
            }
        }
    }

    const float* bhp[4] = { bh0, bh1, bh2, bh3 };
    const int sidx = t * BB + b;
    float pre[4][4];
    #pragma unroll
    for (int g = 0; g < 4; g++){
        #pragma unroll
        for (int h = 0; h < 4; h++){
            const int hid = hq * 4 + h;
            const float xgv = bf2f(xg[(((size_t)g * NSAMP + sidx) * HIDN + hid) * LPP + l]);
            pre[g][h] = acc[g][h] + bhp[g][hid] + xgv;
        }
    }

    #pragma unroll
    for (int h = 0; h < 4; h++){
        const int hid = hq * 4 + h;
        float* cp = cst + ((size_t)b * HIDN + hid) * LPP + l;
        const float cv = first ? 0.f : *cp;
        const float ig = sigmoidf_(pre[0][h]);
        const float fg = sigmoidf_(pre[1][h]);
        const float gg = tanhf_(pre[2][h]);
        const float og = sigmoidf_(pre[3][h]);
        const float cn = fg * cv + ig * gg;
        *cp = cn;
        hout[((size_t)b * HIDN + hid) * LPP + l] = og * tanhf_(cn);
    }
}

// =====================================================================
// Host side
// =====================================================================
extern "C" void kernel_launch(void* const* d_in, const int* in_sizes, int n_in,
                              void* d_out, int out_size, void* d_ws, size_t ws_size,
                              hipStream_t stream)
{
    const float* x = (const float*)d_in[0];

    const float* wxp[4] = {nullptr,nullptr,nullptr,nullptr};
    const float* bxp[4] = {nullptr,nullptr,nullptr,nullptr};
    const float* whp[4] = {nullptr,nullptr,nullptr,nullptr};
    const float* bhp[4] = {nullptr,nullptr,nullptr,nullptr};
    const float* lnw = nullptr; const float* lnb = nullptr;
    int nwx = 0, nwh = 0, pend = -1;
    for (int i = 1; i < n_in; i++){
        const float* p = (const float*)d_in[i];
        const int sz = in_sizes[i];
        if (sz == HIDN * CINC * 3)      { wxp[nwx] = p; pend = 0; }
        else if (sz == HIDN * HIDN * 3) { whp[nwh] = p; pend = 1; }
        else if (sz == HIDN)            { if (pend == 0) bxp[nwx++] = p; else bhp[nwh++] = p; pend = -1; }
        else if (sz == HIDN * LL)       { if (!lnw) lnw = p; else lnb = p; }
    }

    // Workspace: xg (bf16, 256 MiB) then c-state (fp32, 2 MiB).
    unsigned int*   xg_u32 = (unsigned int*)d_ws;
    unsigned short* xg_u16 = (unsigned short*)d_ws;
    const size_t xg_bytes = (size_t)4 * NSAMP * HIDN * LPP * 2;
    float* cst = (float*)((char*)d_ws + xg_bytes);
    float* out = (float*)d_out;

    phase1_kernel<<<dim3(NSAMP, 4), 256, 0, stream>>>(
        x, wxp[0], bxp[0], wxp[1], bxp[1], wxp[2], bxp[2], wxp[3], bxp[3],
        lnw, lnb, xg_u32);

    for (int t = 0; t < TT; t++){
        const float* hprev = (t == 0) ? out : out + (size_t)(t - 1) * BB * HIDN * LPP;
        phase2_kernel<<<dim3(BB, 32), 128, 0, stream>>>(
            hprev, xg_u16,
            whp[0], bhp[0], whp[1], bhp[1], whp[2], bhp[2], whp[3], bhp[3],
            out + (size_t)t * BB * HIDN * LPP, cst, t, (t == 0) ? 1 : 0);
    }
}